// Round 11
// baseline (11185.197 us; speedup 1.0000x reference)
//
#include <hip/hip_runtime.h>

// SimpleRNN: 2-layer ReLU RNN, B=64 T=512 I=256 H=1024 O=1000, fp32 in/out.
// Round 11: r4's proven MALL flag protocol, re-parameterized to kill the 32x
// h-broadcast amplification that made r4/r5 MALL-bandwidth-bound (~24MB/step):
// 8 slices x 128 cols per group-layer (64 blocks x 256 thr). Each block stages
// h into LDS ONCE (coalesced sc0sc1 dwordx4), W_hh/W_ih stream from L2 (plain
// cached loads, L2-hot across steps). ~6.5MB/step MALL traffic (3.7x less).

typedef float f32x4 __attribute__((ext_vector_type(4)));
typedef short bf16x8 __attribute__((ext_vector_type(8)));
typedef unsigned short u16;
typedef unsigned int u32;
typedef u32 u32x4 __attribute__((ext_vector_type(4)));

#define MFMA_BF16(a, b, c) __builtin_amdgcn_mfma_f32_16x16x32_bf16((a), (b), (c), 0, 0, 0)

#define GLDS16(g, l) __builtin_amdgcn_global_load_lds( \
    (const __attribute__((address_space(1))) unsigned int*)(g), \
    (__attribute__((address_space(3))) unsigned int*)(l), 16, 0, 0)

// MALL-coherent 16B load: 32-bit lane offset + SGPR base (coalesced staging)
#define LDGSC(d, voff, sbase) asm volatile( \
    "global_load_dwordx4 %0, %1, %2 sc0 sc1" \
    : "=&v"(d) : "v"(voff), "s"(sbase))
// MALL write-through dword store
#define STORE_SC(p, v) asm volatile("global_store_dword %0, %1, off sc0 sc1" :: "v"(p), "v"(v) : "memory")
// literal-counted vmcnt wait, pinned against scheduler motion
#define WAITVM(n) do { __builtin_amdgcn_sched_barrier(0); \
    asm volatile("s_waitcnt vmcnt(" #n ")" ::: "memory"); \
    __builtin_amdgcn_sched_barrier(0); } while (0)

__device__ __forceinline__ u16 f2b(float f) {  // RNE f32 -> bf16 bits
  unsigned int u = __builtin_bit_cast(unsigned int, f);
  u = (u + 0x7fffu + ((u >> 16) & 1u)) >> 16;
  return (u16)u;
}
__device__ __forceinline__ float b2f(u16 b) {
  unsigned int u = ((unsigned int)b) << 16;
  return __builtin_bit_cast(float, u);
}

// packed u32 = hi-bf16 (low16) | lo-bf16 (high16); extract 8-elem bf16 frags
__device__ __forceinline__ bf16x8 hi_frag(u32x4 d0, u32x4 d1) {
  u32x4 r;
  r[0] = __builtin_amdgcn_perm(d0[1], d0[0], 0x05040100u);
  r[1] = __builtin_amdgcn_perm(d0[3], d0[2], 0x05040100u);
  r[2] = __builtin_amdgcn_perm(d1[1], d1[0], 0x05040100u);
  r[3] = __builtin_amdgcn_perm(d1[3], d1[2], 0x05040100u);
  return __builtin_bit_cast(bf16x8, r);
}
__device__ __forceinline__ bf16x8 lo_frag(u32x4 d0, u32x4 d1) {
  u32x4 r;
  r[0] = __builtin_amdgcn_perm(d0[1], d0[0], 0x07060302u);
  r[1] = __builtin_amdgcn_perm(d0[3], d0[2], 0x07060302u);
  r[2] = __builtin_amdgcn_perm(d1[1], d1[0], 0x07060302u);
  r[3] = __builtin_amdgcn_perm(d1[3], d1[2], 0x07060302u);
  return __builtin_bit_cast(bf16x8, r);
}

// ---------------- elementwise helpers ----------------
__global__ void cast_kernel(const float* __restrict__ s, u16* __restrict__ d, int n4) {
  int i = blockIdx.x * blockDim.x + threadIdx.x;
  if (i >= n4) return;
  float4 v = ((const float4*)s)[i];
  ushort4 o;
  o.x = f2b(v.x); o.y = f2b(v.y); o.z = f2b(v.z); o.w = f2b(v.w);
  ((ushort4*)d)[i] = o;
}

__global__ void bias_kernel(const float* __restrict__ a, const float* __restrict__ b,
                            float* __restrict__ o, int n) {
  int i = blockIdx.x * blockDim.x + threadIdx.x;
  if (i < n) o[i] = a[i] + b[i];
}

// zero ring slot 7 (h(-1)=0) of all 4 groups in both rings + flags, through
// the MALL path so the scan's sc0sc1 loads see them (r4-proven).
__global__ void init_sync_kernel(u32* __restrict__ h0r, u32* __restrict__ h1r,
                                 u32* __restrict__ Fl) {
  int i = blockIdx.x * blockDim.x + threadIdx.x;  // 0..131071
  int g = i >> 14, off = i & 16383;
  u32 z = 0;
  STORE_SC(h0r + g * 131072 + 7 * 16384 + off, z);
  STORE_SC(h1r + g * 131072 + 7 * 16384 + off, z);
  if (i < 64) STORE_SC(Fl + i, z);
}

// ---------------- input GEMM: pre = A @ Bw^T  (A:[M][K], Bw:[1024][K]) ----------------
// rows m=b*512+t -> out row t*64+b (time-major). Out: bf16 [32768][1024].
__global__ __launch_bounds__(256) void gemm_pre(const u16* __restrict__ A,
                                                const u16* __restrict__ Bw,
                                                u16* __restrict__ outp, int K) {
  __shared__ u16 As[128 * 32];
  __shared__ u16 Bs[128 * 32];
  const int tid = threadIdx.x;
  const int lane = tid & 63;
  const int w = tid >> 6;
  const int nt = blockIdx.x & 7;
  const int mt = blockIdx.x >> 3;
  const int m_base = mt * 128;
  const int n_base = nt * 128;

  const int srow = w * 32 + (lane >> 2);
  const int schunk = (lane & 3) ^ (srow & 3);
  const u16* Ag0 = A + (size_t)(m_base + srow) * K + schunk * 8;
  const u16* Ag1 = A + (size_t)(m_base + srow + 16) * K + schunk * 8;
  const u16* Bg0 = Bw + (size_t)(n_base + srow) * K + schunk * 8;
  const u16* Bg1 = Bw + (size_t)(n_base + srow + 16) * K + schunk * 8;
  u16* AsD0 = As + (w * 32) * 32;
  u16* AsD1 = As + (w * 32 + 16) * 32;
  u16* BsD0 = Bs + (w * 32) * 32;
  u16* BsD1 = Bs + (w * 32 + 16) * 32;

  const int wm = (w & 1) * 64;
  const int wn = (w >> 1) * 64;
  const int rl = lane & 15;
  const int q = lane >> 4;

  f32x4 acc[4][4] = {};

  for (int k0 = 0; k0 < K; k0 += 32) {
    __syncthreads();
    GLDS16(Ag0 + k0, AsD0);
    GLDS16(Ag1 + k0, AsD1);
    GLDS16(Bg0 + k0, BsD0);
    GLDS16(Bg1 + k0, BsD1);
    __syncthreads();
    bf16x8 af[4], bfv[4];
#pragma unroll
    for (int i = 0; i < 4; ++i) {
      int ra = wm + i * 16 + rl;
      af[i] = *(const bf16x8*)(As + ra * 32 + ((q ^ (ra & 3)) << 3));
      int rb = wn + i * 16 + rl;
      bfv[i] = *(const bf16x8*)(Bs + rb * 32 + ((q ^ (rb & 3)) << 3));
    }
#pragma unroll
    for (int i = 0; i < 4; ++i)
#pragma unroll
      for (int j = 0; j < 4; ++j)
        acc[i][j] = MFMA_BF16(af[i], bfv[j], acc[i][j]);
  }

#pragma unroll
  for (int i = 0; i < 4; ++i)
#pragma unroll
    for (int j = 0; j < 4; ++j)
#pragma unroll
      for (int r = 0; r < 4; ++r) {
        int gm = m_base + wm + i * 16 + q * 4 + r;
        int gn = n_base + wn + j * 16 + rl;
        int orow = ((gm & 511) << 6) | (gm >> 9);
        outp[(size_t)orow * 1024 + gn] = f2b(acc[i][j][r]);
      }
}

// ---------------- fused 2-layer persistent scan, low-amplification ----------
// 64 blocks x 256 threads (4 waves). bid = g*16 + role; role 0..7 = L0 slice,
// 8..15 = L1 slice; slice owns 128 cols (wave wid: cols c0+wid*32 .. +31).
// Per step: wave0 polls flags -> block stages h into LDS (coalesced sc0sc1)
// -> waves compute full-K from LDS with W streamed from L2 -> store + flag.
// Rings: [4 grp][8 slots][16 rows][1024] packed u32 (hi|lo<<16).
__global__ __launch_bounds__(256, 1) void fused_scan(
    const u16* __restrict__ whh0, const u16* __restrict__ whh1,
    const u16* __restrict__ wih1, const u16* __restrict__ pre0,
    const float* __restrict__ bv0, const float* __restrict__ bv1,
    u32* h0ring, u32* h1ring, u32* Fl, u32* __restrict__ hlast) {
  __shared__ u32 hs[2][16][1024];  // 128KB: [0]=h0 (L0: h0(t-1); L1: h0(t)), [1]=h1(t-1)

  const int bid = blockIdx.x;
  const int g = bid >> 4;        // group 0..3 (16 batch rows)
  const int role = bid & 15;     // 0..7 L0, 8..15 L1
  const bool isL0 = role < 8;
  const int s = role & 7;
  const int c0 = s * 128;
  const int tid = threadIdx.x;
  const int lane = tid & 63;
  const int wid = tid >> 6;
  const int rl = lane & 15;
  const int q = lane >> 4;
  const int c0w = c0 + wid * 32;
  const int b0 = g * 16;

  const float* bv = isL0 ? bv0 : bv1;
  const float bias0 = bv[c0w + rl];
  const float bias1 = bv[c0w + 16 + rl];

  const u16* whh = isL0 ? whh0 : whh1;
  const u16* wh0p = whh + (size_t)(c0w + rl) * 1024 + q * 8;
  const u16* wh1p = wh0p + 16 * 1024;
  const u16* wi0p = wih1 + (size_t)(c0w + rl) * 1024 + q * 8;
  const u16* wi1p = wi0p + 16 * 1024;

  u32* fown = Fl + g * 16 + role;
  const u32* fpoll = Fl + g * 16 + (lane & 15);
  // L0 at t: L0 sibs >= t (data dep), L1 >= t-7 (ring-8 backpressure).
  // L1 at t: L0 >= t+1 (h0(t) ready), L1 sibs >= t.
  const int tgt_off = isL0 ? (((lane & 15) < 8) ? 0 : -7)
                           : (((lane & 15) < 8) ? 1 : 0);

  u32* h0g = h0ring + g * 131072;  // [8][16][1024]
  u32* h1g = h1ring + g * 131072;

  for (int t = 0; t < 512; ++t) {
    // pre0 prefetch (plain cached; overlaps poll, drained by staging WAITVM)
    u16 praw[8];
    if (isL0) {
      const u16* pt = pre0 + (size_t)t * 65536 + (b0 + q * 4) * 1024 + c0w + rl;
#pragma unroll
      for (int r = 0; r < 4; ++r) {
        praw[r] = pt[r * 1024];
        praw[4 + r] = pt[r * 1024 + 16];
      }
    }

    // ---- wave0: bounded flag poll (r4-proven protocol) ----
    if (wid == 0) {
      const int tgt = t + tgt_off;
      for (int it = 0; it < 16384; ++it) {
        int fv;
        asm volatile("global_load_dword %0, %1, off sc0 sc1\n\t"
                     "s_waitcnt vmcnt(0)"
                     : "=v"(fv) : "v"(fpoll) : "memory");
        if (__all(fv >= tgt)) break;
        __builtin_amdgcn_s_sleep(1);
      }
      __builtin_amdgcn_sched_barrier(0);
    }
    __syncthreads();  // release all waves

    // ---- cooperative h staging: global (sc0sc1, coalesced) -> LDS swizzled
    // thread tid stages chunk tid of row j (chunk = 16B = 4 u32);
    // LDS chunk index = tid ^ (j&7)  (bank-spread for the A-frag reads).
    {
      const u32* src0 = isL0 ? (h0g + ((t + 7) & 7) * 16384)
                             : (h0g + (t & 7) * 16384);
      u32x4 st[16];
#pragma unroll
      for (int j = 0; j < 16; ++j) {
        u32 voff = (u32)((j * 256 + tid) * 16);
        LDGSC(st[j], voff, src0);
      }
      if (!isL0) {
        const u32* src1 = h1g + ((t + 7) & 7) * 16384;
        u32x4 st2[16];
#pragma unroll
        for (int j = 0; j < 16; ++j) {
          u32 voff = (u32)((j * 256 + tid) * 16);
          LDGSC(st2[j], voff, src1);
        }
        WAITVM(0);
#pragma unroll
        for (int j = 0; j < 16; ++j) {
          *(u32x4*)&hs[0][j][(u32)((tid ^ (j & 7)) << 2)] = st[j];
          *(u32x4*)&hs[1][j][(u32)((tid ^ (j & 7)) << 2)] = st2[j];
        }
      } else {
        WAITVM(0);
#pragma unroll
        for (int j = 0; j < 16; ++j)
          *(u32x4*)&hs[0][j][(u32)((tid ^ (j & 7)) << 2)] = st[j];
      }
    }
    __syncthreads();

    // ---- compute: full K from LDS; W fragments streamed from L2 ----
    f32x4 acc0 = {0.f, 0.f, 0.f, 0.f}, acc1 = {0.f, 0.f, 0.f, 0.f};
    const int swz = rl & 7;
    if (isL0) {
#pragma unroll
      for (int kt = 0; kt < 32; ++kt) {
        int cb = q * 2 + kt * 8;
        u32x4 d0 = *(const u32x4*)&hs[0][rl][(u32)((cb ^ swz) << 2)];
        u32x4 d1 = *(const u32x4*)&hs[0][rl][(u32)(((cb + 1) ^ swz) << 2)];
        bf16x8 ah = hi_frag(d0, d1);
        bf16x8 al = lo_frag(d0, d1);
        bf16x8 w0 = *(const bf16x8*)(wh0p + kt * 32);
        bf16x8 w1 = *(const bf16x8*)(wh1p + kt * 32);
        acc0 = MFMA_BF16(ah, w0, acc0); acc0 = MFMA_BF16(al, w0, acc0);
        acc1 = MFMA_BF16(ah, w1, acc1); acc1 = MFMA_BF16(al, w1, acc1);
      }
    } else {
#pragma unroll
      for (int kt = 0; kt < 32; ++kt) {
        int cb = q * 2 + kt * 8;
        u32x4 e0 = *(const u32x4*)&hs[0][rl][(u32)((cb ^ swz) << 2)];
        u32x4 e1 = *(const u32x4*)&hs[0][rl][(u32)(((cb + 1) ^ swz) << 2)];
        u32x4 d0 = *(const u32x4*)&hs[1][rl][(u32)((cb ^ swz) << 2)];
        u32x4 d1 = *(const u32x4*)&hs[1][rl][(u32)(((cb + 1) ^ swz) << 2)];
        bf16x8 a0h = hi_frag(e0, e1);
        bf16x8 a1h = hi_frag(d0, d1);
        bf16x8 a1l = lo_frag(d0, d1);
        bf16x8 wh0 = *(const bf16x8*)(wh0p + kt * 32);
        bf16x8 wh1 = *(const bf16x8*)(wh1p + kt * 32);
        bf16x8 wi0 = *(const bf16x8*)(wi0p + kt * 32);
        bf16x8 wi1 = *(const bf16x8*)(wi1p + kt * 32);
        acc0 = MFMA_BF16(a1h, wh0, acc0); acc0 = MFMA_BF16(a1l, wh0, acc0);
        acc0 = MFMA_BF16(a0h, wi0, acc0);
        acc1 = MFMA_BF16(a1h, wh1, acc1); acc1 = MFMA_BF16(a1l, wh1, acc1);
        acc1 = MFMA_BF16(a0h, wi1, acc1);
      }
    }

    // ---- epilogue: h = relu(acc + (pre|0) + bias), pack hi|lo, store MALL
    {
      u32* wb = (isL0 ? h0g : h1g) + (t & 7) * 16384 + (q * 4) * 1024 + c0w + rl;
      u32 pk[8];
#pragma unroll
      for (int r = 0; r < 4; ++r) {
        float v0 = acc0[r] + bias0;
        float v1 = acc1[r] + bias1;
        if (isL0) { v0 += b2f(praw[r]); v1 += b2f(praw[4 + r]); }
        v0 = fmaxf(v0, 0.f);
        v1 = fmaxf(v1, 0.f);
        u16 h = f2b(v0);
        u16 l = f2b(v0 - b2f(h));
        pk[r] = (u32)h | ((u32)l << 16);
        STORE_SC(wb + r * 1024, pk[r]);
        u16 h2 = f2b(v1);
        u16 l2 = f2b(v1 - b2f(h2));
        pk[4 + r] = (u32)h2 | ((u32)l2 << 16);
        STORE_SC(wb + r * 1024 + 16, pk[4 + r]);
      }
      if (!isL0 && t == 511) {  // export final h1 (plain path) for the head
        u32* hl = hlast + (b0 + q * 4) * 1024 + c0w + rl;
#pragma unroll
        for (int r = 0; r < 4; ++r) {
          hl[r * 1024] = pk[r];
          hl[r * 1024 + 16] = pk[4 + r];
        }
      }
    }
    // drain this wave's stores, block-wide barrier, then publish the flag
    WAITVM(0);
    __syncthreads();
    if (tid == 0) STORE_SC(fown, (u32)(t + 1));
  }
}

// ---------------- head: logits = h1_last @ w_lin^T + b_lin ----------------
__global__ __launch_bounds__(64) void logits_kernel(const u32* __restrict__ hpk,  // packed [64][1024]
                                                    const u16* __restrict__ wl,   // [1008][1024]
                                                    const float* __restrict__ blin,
                                                    float* __restrict__ lg) {     // [64][1008]
  const int wgn = blockIdx.x;  // 0..62
  const int lane = threadIdx.x;
  const int rl = lane & 15;
  const int q = lane >> 4;
  f32x4 acc[4] = {};
  const u16* brow = wl + (size_t)(wgn * 16 + rl) * 1024 + q * 8;
  for (int kt = 0; kt < 32; ++kt) {
    bf16x8 bfv = *(const bf16x8*)(brow + kt * 32);
#pragma unroll
    for (int mi = 0; mi < 4; ++mi) {
      const u32* hp = hpk + (mi * 16 + rl) * 1024 + kt * 32 + q * 8;
      u32x4 d0 = *(const u32x4*)hp;
      u32x4 d1 = *(const u32x4*)(hp + 4);
      acc[mi] = MFMA_BF16(hi_frag(d0, d1), bfv, acc[mi]);
      acc[mi] = MFMA_BF16(lo_frag(d0, d1), bfv, acc[mi]);
    }
  }
  int col = wgn * 16 + rl;
  float bb = (col < 1000) ? blin[col] : 0.f;
#pragma unroll
  for (int mi = 0; mi < 4; ++mi)
#pragma unroll
    for (int r = 0; r < 4; ++r) {
      int row = mi * 16 + q * 4 + r;
      lg[row * 1008 + col] = acc[mi][r] + bb;
    }
}

__global__ __launch_bounds__(64) void lsm_kernel(const float* __restrict__ lg,
                                                 float* __restrict__ outp) {
  const int b = blockIdx.x;
  const int lane = threadIdx.x;
  float x[16];
  float m = -1e30f;
#pragma unroll
  for (int i = 0; i < 16; ++i) {
    int o = lane + i * 64;
    x[i] = (o < 1000) ? lg[b * 1008 + o] : -1e30f;
    m = fmaxf(m, x[i]);
  }
  for (int s = 32; s > 0; s >>= 1) m = fmaxf(m, __shfl_xor(m, s, 64));
  float sum = 0.f;
#pragma unroll
  for (int i = 0; i < 16; ++i) sum += expf(x[i] - m);
  for (int s = 32; s > 0; s >>= 1) sum += __shfl_xor(sum, s, 64);
  float lse = m + logf(sum);
#pragma unroll
  for (int i = 0; i < 16; ++i) {
    int o = lane + i * 64;
    if (o < 1000) outp[b * 1000 + o] = x[i] - lse;
  }
}

// ---------------- launch ----------------
extern "C" void kernel_launch(void* const* d_in, const int* in_sizes, int n_in,
                              void* d_out, int out_size, void* d_ws, size_t ws_size,
                              hipStream_t stream) {
  (void)in_sizes; (void)n_in; (void)out_size;
  const int B = 64, T = 512, I = 256, H = 1024, O = 1000;

  const float* x = (const float*)d_in[0];
  const float* w_ih0 = (const float*)d_in[1];
  const float* w_hh0 = (const float*)d_in[2];
  const float* b_ih0 = (const float*)d_in[3];
  const float* b_hh0 = (const float*)d_in[4];
  const float* w_ih1 = (const float*)d_in[5];
  const float* w_hh1 = (const float*)d_in[6];
  const float* b_ih1 = (const float*)d_in[7];
  const float* b_hh1 = (const float*)d_in[8];
  const float* w_lin = (const float*)d_in[9];
  const float* b_lin = (const float*)d_in[10];

  size_t off = 0;
  char* ws = (char*)d_ws;
  auto take = [&](size_t bytes) -> void* {
    void* p = ws + off;
    off += (bytes + 255) & ~(size_t)255;
    return p;
  };
  u16* pre = (u16*)take((size_t)T * B * H * 2);   // 64MB
  u16* xbf = (u16*)take((size_t)B * T * I * 2);   // 16MB
  u16* wih0b = (u16*)take((size_t)H * I * 2);
  u16* whh0b = (u16*)take((size_t)H * H * 2);
  u16* wih1b = (u16*)take((size_t)H * H * 2);
  u16* whh1b = (u16*)take((size_t)H * H * 2);
  u16* wlinb = (u16*)take((size_t)1008 * H * 2);
  float* bv0 = (float*)take((size_t)H * 4);
  float* bv1 = (float*)take((size_t)H * 4);
  u32* h0ring = (u32*)take((size_t)4 * 8 * 16 * H * 4);  // 2MB: [4g][8slot][16][1024]
  u32* h1ring = (u32*)take((size_t)4 * 8 * 16 * H * 4);
  u32* hlast = (u32*)take((size_t)B * H * 4);            // packed h1(T-1)
  u32* Fl = (u32*)take((size_t)64 * 4);
  float* lgt = (float*)take((size_t)B * 1008 * 4);
  if (off > ws_size) return;

  // casts
  cast_kernel<<<(B * T * I / 4) / 256, 256, 0, stream>>>(x, xbf, B * T * I / 4);
  cast_kernel<<<(H * I / 4) / 256, 256, 0, stream>>>(w_ih0, wih0b, H * I / 4);
  cast_kernel<<<(H * H / 4) / 256, 256, 0, stream>>>(w_hh0, whh0b, H * H / 4);
  cast_kernel<<<(H * H / 4) / 256, 256, 0, stream>>>(w_ih1, wih1b, H * H / 4);
  cast_kernel<<<(H * H / 4) / 256, 256, 0, stream>>>(w_hh1, whh1b, H * H / 4);
  cast_kernel<<<(O * H / 4) / 256, 256, 0, stream>>>(w_lin, wlinb, O * H / 4);
  bias_kernel<<<4, 256, 0, stream>>>(b_ih0, b_hh0, bv0, H);
  bias_kernel<<<4, 256, 0, stream>>>(b_ih1, b_hh1, bv1, H);

  init_sync_kernel<<<512, 256, 0, stream>>>(h0ring, h1ring, Fl);

  gemm_pre<<<dim3((B * T / 128) * (H / 128)), 256, 0, stream>>>(xbf, wih0b, pre, I);

  // persistent fused scan: 64 blocks x 256 thr, 128KB LDS -> 1 block/CU,
  // 64 CUs busy, all co-resident.
  fused_scan<<<64, 256, 0, stream>>>(whh0b, whh1b, wih1b, pre, bv0, bv1,
                                     h0ring, h1ring, Fl, hlast);

  logits_kernel<<<63, 64, 0, stream>>>(hlast, wlinb, b_lin, lgt);
  lsm_kernel<<<64, 64, 0, stream>>>(lgt, (float*)d_out);
}

// Round 12
// 3916.076 us; speedup vs baseline: 2.8562x; 2.8562x over previous
//
#include <hip/hip_runtime.h>

// SimpleRNN: 2-layer ReLU RNN, B=64 T=512 I=256 H=1024 O=1000, fp32 in/out.
// Round 12: EXACTLY round-4's passing kernel (4.83ms), with one change driven
// by r4's counters (FETCH 1.125GB ~= 64MB pre0 + 2MB x 512 = W_ih1 re-fetched
// from HBM EVERY step, stalling the L1 ladder): L1 blocks stage their W_ih1
// slice into LDS once (128KB total LDS, proven viable in r11), and the L1
// ladder drops its cached W loads (24 -> 16 loads/phase, 3-deep).

typedef float f32x4 __attribute__((ext_vector_type(4)));
typedef short bf16x8 __attribute__((ext_vector_type(8)));
typedef unsigned short u16;
typedef unsigned int u32;
typedef u32 u32x4 __attribute__((ext_vector_type(4)));

#define MFMA_BF16(a, b, c) __builtin_amdgcn_mfma_f32_16x16x32_bf16((a), (b), (c), 0, 0, 0)

#define GLDS16(g, l) __builtin_amdgcn_global_load_lds( \
    (const __attribute__((address_space(1))) unsigned int*)(g), \
    (__attribute__((address_space(3))) unsigned int*)(l), 16, 0, 0)

// two cache-bypassing (coherent at MALL) 16B loads from one base + literal offsets
#define LD2SC(d0, d1, b_, O1, O2) asm volatile( \
    "global_load_dwordx4 %0, %2, off offset:" O1 " sc0 sc1\n\t" \
    "global_load_dwordx4 %1, %2, off offset:" O2 " sc0 sc1" \
    : "=&v"(d0), "=&v"(d1) : "v"(b_))
// cache-bypassing dword store (write-through to MALL)
#define STORE_SC(p, v) asm volatile("global_store_dword %0, %1, off sc0 sc1" :: "v"(p), "v"(v) : "memory")
// literal-counted vmcnt wait, pinned against scheduler motion
#define WAITVM(n) do { __builtin_amdgcn_sched_barrier(0); \
    asm volatile("s_waitcnt vmcnt(" #n ")" ::: "memory"); \
    __builtin_amdgcn_sched_barrier(0); } while (0)

__device__ __forceinline__ u16 f2b(float f) {  // RNE f32 -> bf16 bits
  unsigned int u = __builtin_bit_cast(unsigned int, f);
  u = (u + 0x7fffu + ((u >> 16) & 1u)) >> 16;
  return (u16)u;
}
__device__ __forceinline__ float b2f(u16 b) {
  unsigned int u = ((unsigned int)b) << 16;
  return __builtin_bit_cast(float, u);
}

// packed u32 = hi-bf16 (low16) | lo-bf16 (high16); extract 8-elem bf16 frags
__device__ __forceinline__ bf16x8 hi_frag(u32x4 d0, u32x4 d1) {
  u32x4 r;
  r[0] = __builtin_amdgcn_perm(d0[1], d0[0], 0x05040100u);
  r[1] = __builtin_amdgcn_perm(d0[3], d0[2], 0x05040100u);
  r[2] = __builtin_amdgcn_perm(d1[1], d1[0], 0x05040100u);
  r[3] = __builtin_amdgcn_perm(d1[3], d1[2], 0x05040100u);
  return __builtin_bit_cast(bf16x8, r);
}
__device__ __forceinline__ bf16x8 lo_frag(u32x4 d0, u32x4 d1) {
  u32x4 r;
  r[0] = __builtin_amdgcn_perm(d0[1], d0[0], 0x07060302u);
  r[1] = __builtin_amdgcn_perm(d0[3], d0[2], 0x07060302u);
  r[2] = __builtin_amdgcn_perm(d1[1], d1[0], 0x07060302u);
  r[3] = __builtin_amdgcn_perm(d1[3], d1[2], 0x07060302u);
  return __builtin_bit_cast(bf16x8, r);
}

// ---------------- elementwise helpers ----------------
__global__ void cast_kernel(const float* __restrict__ s, u16* __restrict__ d, int n4) {
  int i = blockIdx.x * blockDim.x + threadIdx.x;
  if (i >= n4) return;
  float4 v = ((const float4*)s)[i];
  ushort4 o;
  o.x = f2b(v.x); o.y = f2b(v.y); o.z = f2b(v.z); o.w = f2b(v.w);
  ((ushort4*)d)[i] = o;
}

__global__ void bias_kernel(const float* __restrict__ a, const float* __restrict__ b,
                            float* __restrict__ o, int n) {
  int i = blockIdx.x * blockDim.x + threadIdx.x;
  if (i < n) o[i] = a[i] + b[i];
}

// zero h-buffers and flags THROUGH THE BYPASS PATH (sc0 sc1) so the scan's
// bypass loads see them (normal-path zeros are invisible to bypass reads).
__global__ void init_sync_kernel(u32* h0, u32* h1, u32* F0f, u32* F1f) {
  int i = blockIdx.x * blockDim.x + threadIdx.x;  // 0..262143
  u32 z = 0;
  STORE_SC(h0 + i, z);
  STORE_SC(h1 + i, z);
  if (i < 128) { STORE_SC(F0f + i, z); STORE_SC(F1f + i, z); }
}

// ---------------- input GEMM: pre = A @ Bw^T  (A:[M][K], Bw:[1024][K]) ----------------
// rows m=b*512+t -> out row t*64+b (time-major). Out: bf16 [32768][1024].
__global__ __launch_bounds__(256) void gemm_pre(const u16* __restrict__ A,
                                                const u16* __restrict__ Bw,
                                                u16* __restrict__ outp, int K) {
  __shared__ u16 As[128 * 32];
  __shared__ u16 Bs[128 * 32];
  const int tid = threadIdx.x;
  const int lane = tid & 63;
  const int w = tid >> 6;
  const int nt = blockIdx.x & 7;
  const int mt = blockIdx.x >> 3;
  const int m_base = mt * 128;
  const int n_base = nt * 128;

  const int srow = w * 32 + (lane >> 2);
  const int schunk = (lane & 3) ^ (srow & 3);
  const u16* Ag0 = A + (size_t)(m_base + srow) * K + schunk * 8;
  const u16* Ag1 = A + (size_t)(m_base + srow + 16) * K + schunk * 8;
  const u16* Bg0 = Bw + (size_t)(n_base + srow) * K + schunk * 8;
  const u16* Bg1 = Bw + (size_t)(n_base + srow + 16) * K + schunk * 8;
  u16* AsD0 = As + (w * 32) * 32;
  u16* AsD1 = As + (w * 32 + 16) * 32;
  u16* BsD0 = Bs + (w * 32) * 32;
  u16* BsD1 = Bs + (w * 32 + 16) * 32;

  const int wm = (w & 1) * 64;
  const int wn = (w >> 1) * 64;
  const int rl = lane & 15;
  const int q = lane >> 4;

  f32x4 acc[4][4] = {};

  for (int k0 = 0; k0 < K; k0 += 32) {
    __syncthreads();
    GLDS16(Ag0 + k0, AsD0);
    GLDS16(Ag1 + k0, AsD1);
    GLDS16(Bg0 + k0, BsD0);
    GLDS16(Bg1 + k0, BsD1);
    __syncthreads();
    bf16x8 af[4], bfv[4];
#pragma unroll
    for (int i = 0; i < 4; ++i) {
      int ra = wm + i * 16 + rl;
      af[i] = *(const bf16x8*)(As + ra * 32 + ((q ^ (ra & 3)) << 3));
      int rb = wn + i * 16 + rl;
      bfv[i] = *(const bf16x8*)(Bs + rb * 32 + ((q ^ (rb & 3)) << 3));
    }
#pragma unroll
    for (int i = 0; i < 4; ++i)
#pragma unroll
      for (int j = 0; j < 4; ++j)
        acc[i][j] = MFMA_BF16(af[i], bfv[j], acc[i][j]);
  }

#pragma unroll
  for (int i = 0; i < 4; ++i)
#pragma unroll
    for (int j = 0; j < 4; ++j)
#pragma unroll
      for (int r = 0; r < 4; ++r) {
        int gm = m_base + wm + i * 16 + q * 4 + r;
        int gn = n_base + wn + j * 16 + rl;
        int orow = ((gm & 511) << 6) | (gm >> 9);
        outp[(size_t)orow * 1024 + gn] = f2b(acc[i][j][r]);
      }
}

// ---------------- fused 2-layer persistent scan (r4 + Wih-in-LDS) ----------
// 256 blocks x 64 threads (1 wave). bid<128: layer-0 role; else layer-1.
// Role (g, s): group g = 16 batch rows, slice s = 32 output cols.
// W_hh slice (64KB) + (L1 only) W_ih1 slice (64KB) LDS-resident. h exchanged
// as packed u32 (bf16 hi | lo<<16) through MALL sc0/sc1; per-slice flags.
__global__ __launch_bounds__(64, 1) void fused_scan(
    const u16* __restrict__ whh0, const u16* __restrict__ whh1,
    const u16* __restrict__ wih1, const u16* __restrict__ pre0,
    const float* __restrict__ bv0, const float* __restrict__ bv1,
    u32* h0buf, u32* h1buf, u32* F0, u32* F1, u32* __restrict__ hlast) {
  __shared__ u16 Wl[32 * 1024];  // 64KB: W_hh slice
  __shared__ u16 Wi[32 * 1024];  // 64KB: W_ih1 slice (L1 blocks only)

  const int bid = blockIdx.x;
  const bool isL0 = bid < 128;
  const int rb = isL0 ? bid : (bid - 128);
  const int g = rb >> 5;
  const int s = rb & 31;
  const int b0 = g * 16;
  const int c0 = s * 32;
  const int lane = threadIdx.x;
  const int rl = lane & 15;
  const int q = lane >> 4;

  // stage W_hh slice (rows c0..c0+31), 16B-chunk XOR swizzle by (n&7)
  {
    const u16* wsrc = isL0 ? whh0 : whh1;
#pragma unroll 4
    for (int i = 0; i < 64; ++i) {
      int idx = i * 64 + lane;
      int n = idx >> 7;
      int c = idx & 127;
      bf16x8 v = *(const bf16x8*)(wsrc + (size_t)(c0 + n) * 1024 + c * 8);
      *(bf16x8*)(Wl + n * 1024 + ((c ^ (n & 7)) << 3)) = v;
    }
    if (!isL0) {
#pragma unroll 4
      for (int i = 0; i < 64; ++i) {
        int idx = i * 64 + lane;
        int n = idx >> 7;
        int c = idx & 127;
        bf16x8 v = *(const bf16x8*)(wih1 + (size_t)(c0 + n) * 1024 + c * 8);
        *(bf16x8*)(Wi + n * 1024 + ((c ^ (n & 7)) << 3)) = v;
      }
    }
    __syncthreads();
  }

  const float* bv = isL0 ? bv0 : bv1;
  const float bias0 = bv[c0 + rl];
  const float bias1 = bv[c0 + 16 + rl];

  u32* fown_ptr = (isL0 ? F0 : F1) + g * 32 + s;
  const u32* fpoll = (lane < 32) ? (F0 + g * 32 + lane) : (F1 + g * 32 + (lane & 31));
  const int dA = isL0 ? 0 : 1;   // F0 target offset
  const int dB = isL0 ? -3 : 0;  // F1 target offset
  const int mytgt_sel = (lane < 32) ? dA : dB;

  const int hrow_off = (b0 + rl) * 1024 + q * 8;
  const int wrow_off = (b0 + q * 4) * 1024 + c0 + rl;

  for (int t = 0; t < 512; ++t) {
    // L0 pre0 prefetch (normal loads) BEFORE the poll; the poll's vmcnt(0)
    // drains them so the ladder's counts start from zero outstanding.
    u16 praw[8];
    if (isL0) {
      const u16* pt = pre0 + (size_t)t * 65536 + wrow_off;
#pragma unroll
      for (int r = 0; r < 4; ++r) {
        praw[r] = pt[r * 1024];
        praw[4 + r] = pt[r * 1024 + 16];
      }
    }

    // ---- wait for dependencies (flags = monotonic step counters) ----
    {
      int tgt = t + mytgt_sel;
      while (true) {
        int fv;
        asm volatile("global_load_dword %0, %1, off sc0 sc1\n\t"
                     "s_waitcnt vmcnt(0)"
                     : "=v"(fv) : "v"(fpoll) : "memory");
        if (__all(fv >= tgt)) break;
        __builtin_amdgcn_s_sleep(4);
      }
      __builtin_amdgcn_sched_barrier(0);
    }

    if (isL0) {
      // ================= layer-0 step =================
      f32x4 acc0 = {0.f, 0.f, 0.f, 0.f}, acc1 = {0.f, 0.f, 0.f, 0.f};
      const u32* hp = h0buf + ((t + 3) & 3) * 65536 + hrow_off;
      u32x4 st[3][8];  // 96 VGPRs staging, 3-deep
#define L0_ISSUE(B) do { \
      const u32* bb_ = hp + (B) * 128; \
      LD2SC(st[(B) % 3][0], st[(B) % 3][1], bb_, "0", "16"); \
      LD2SC(st[(B) % 3][2], st[(B) % 3][3], bb_, "128", "144"); \
      LD2SC(st[(B) % 3][4], st[(B) % 3][5], bb_, "256", "272"); \
      LD2SC(st[(B) % 3][6], st[(B) % 3][7], bb_, "384", "400"); } while (0)
#define L0_COMP(B) _Pragma("unroll") for (int i = 0; i < 4; ++i) { \
      int kt_ = (B) * 4 + i; \
      bf16x8 ah = hi_frag(st[(B) % 3][2 * i], st[(B) % 3][2 * i + 1]); \
      bf16x8 al = lo_frag(st[(B) % 3][2 * i], st[(B) % 3][2 * i + 1]); \
      int cc_ = ((kt_ * 4 + q) ^ (rl & 7)) << 3; \
      bf16x8 w0_ = *(const bf16x8*)(Wl + rl * 1024 + cc_); \
      bf16x8 w1_ = *(const bf16x8*)(Wl + (16 + rl) * 1024 + cc_); \
      acc0 = MFMA_BF16(ah, w0_, acc0); acc0 = MFMA_BF16(al, w0_, acc0); \
      acc1 = MFMA_BF16(ah, w1_, acc1); acc1 = MFMA_BF16(al, w1_, acc1); }
      L0_ISSUE(0); L0_ISSUE(1); L0_ISSUE(2);
      WAITVM(16); L0_COMP(0) L0_ISSUE(3);
      WAITVM(16); L0_COMP(1) L0_ISSUE(4);
      WAITVM(16); L0_COMP(2) L0_ISSUE(5);
      WAITVM(16); L0_COMP(3) L0_ISSUE(6);
      WAITVM(16); L0_COMP(4) L0_ISSUE(7);
      WAITVM(16); L0_COMP(5)
      WAITVM(8);  L0_COMP(6)
      WAITVM(0);  L0_COMP(7)
#undef L0_ISSUE
#undef L0_COMP
      // epilogue: h0 = relu(acc + pre + bias) -> packed hi|lo to MALL
      u32* wb = h0buf + (t & 3) * 65536 + wrow_off;
#pragma unroll
      for (int r = 0; r < 4; ++r) {
        float v0 = acc0[r] + b2f(praw[r]) + bias0;
        v0 = fmaxf(v0, 0.f);
        u16 h = f2b(v0);
        u16 l = f2b(v0 - b2f(h));
        STORE_SC(wb + r * 1024, (u32)h | ((u32)l << 16));
        float v1 = acc1[r] + b2f(praw[4 + r]) + bias1;
        v1 = fmaxf(v1, 0.f);
        u16 h2 = f2b(v1);
        u16 l2 = f2b(v1 - b2f(h2));
        STORE_SC(wb + r * 1024 + 16, (u32)h2 | ((u32)l2 << 16));
      }
    } else {
      // ================= layer-1 step =================
      f32x4 acc0 = {0.f, 0.f, 0.f, 0.f}, acc1 = {0.f, 0.f, 0.f, 0.f};
      const u32* h0p = h0buf + (t & 3) * 65536 + hrow_off;
      const u32* h1p = h1buf + ((t + 3) & 3) * 65536 + hrow_off;
      u32x4 s0[3][8], s1[3][8];  // 192 VGPRs staging, 3-deep, 16 loads/phase
#define L1_ISSUE(B) do { \
      const u32* a0b_ = h0p + (B) * 128; \
      const u32* a1b_ = h1p + (B) * 128; \
      LD2SC(s0[(B) % 3][0], s0[(B) % 3][1], a0b_, "0", "16"); \
      LD2SC(s1[(B) % 3][0], s1[(B) % 3][1], a1b_, "0", "16"); \
      LD2SC(s0[(B) % 3][2], s0[(B) % 3][3], a0b_, "128", "144"); \
      LD2SC(s1[(B) % 3][2], s1[(B) % 3][3], a1b_, "128", "144"); \
      LD2SC(s0[(B) % 3][4], s0[(B) % 3][5], a0b_, "256", "272"); \
      LD2SC(s1[(B) % 3][4], s1[(B) % 3][5], a1b_, "256", "272"); \
      LD2SC(s0[(B) % 3][6], s0[(B) % 3][7], a0b_, "384", "400"); \
      LD2SC(s1[(B) % 3][6], s1[(B) % 3][7], a1b_, "384", "400"); } while (0)
#define L1_COMP(B) _Pragma("unroll") for (int i = 0; i < 4; ++i) { \
      int kt_ = (B) * 4 + i; \
      bf16x8 a0h = hi_frag(s0[(B) % 3][2 * i], s0[(B) % 3][2 * i + 1]); \
      bf16x8 a1h = hi_frag(s1[(B) % 3][2 * i], s1[(B) % 3][2 * i + 1]); \
      bf16x8 a1l = lo_frag(s1[(B) % 3][2 * i], s1[(B) % 3][2 * i + 1]); \
      int cc_ = ((kt_ * 4 + q) ^ (rl & 7)) << 3; \
      bf16x8 wh0_ = *(const bf16x8*)(Wl + rl * 1024 + cc_); \
      bf16x8 wh1_ = *(const bf16x8*)(Wl + (16 + rl) * 1024 + cc_); \
      bf16x8 wi0_ = *(const bf16x8*)(Wi + rl * 1024 + cc_); \
      bf16x8 wi1_ = *(const bf16x8*)(Wi + (16 + rl) * 1024 + cc_); \
      acc0 = MFMA_BF16(a1h, wh0_, acc0); acc0 = MFMA_BF16(a1l, wh0_, acc0); \
      acc0 = MFMA_BF16(a0h, wi0_, acc0); \
      acc1 = MFMA_BF16(a1h, wh1_, acc1); acc1 = MFMA_BF16(a1l, wh1_, acc1); \
      acc1 = MFMA_BF16(a0h, wi1_, acc1); }
      L1_ISSUE(0); L1_ISSUE(1); L1_ISSUE(2);
      WAITVM(32); L1_COMP(0) L1_ISSUE(3);
      WAITVM(32); L1_COMP(1) L1_ISSUE(4);
      WAITVM(32); L1_COMP(2) L1_ISSUE(5);
      WAITVM(32); L1_COMP(3) L1_ISSUE(6);
      WAITVM(32); L1_COMP(4) L1_ISSUE(7);
      WAITVM(32); L1_COMP(5)
      WAITVM(16); L1_COMP(6)
      WAITVM(0);  L1_COMP(7)
#undef L1_ISSUE
#undef L1_COMP
      u32* wb = h1buf + (t & 3) * 65536 + wrow_off;
      u32 pk[8];
#pragma unroll
      for (int r = 0; r < 4; ++r) {
        float v0 = acc0[r] + bias0;
        v0 = fmaxf(v0, 0.f);
        u16 h = f2b(v0);
        u16 l = f2b(v0 - b2f(h));
        pk[r] = (u32)h | ((u32)l << 16);
        STORE_SC(wb + r * 1024, pk[r]);
        float v1 = acc1[r] + bias1;
        v1 = fmaxf(v1, 0.f);
        u16 h2 = f2b(v1);
        u16 l2 = f2b(v1 - b2f(h2));
        pk[4 + r] = (u32)h2 | ((u32)l2 << 16);
        STORE_SC(wb + r * 1024 + 16, pk[4 + r]);
      }
      if (t == 511) {  // export final h1 via the normal path for the head
        u32* hl = hlast + wrow_off;
#pragma unroll
        for (int r = 0; r < 4; ++r) {
          hl[r * 1024] = pk[r];
          hl[r * 1024 + 16] = pk[4 + r];
        }
      }
    }
    // drain h-stores to the coherence point, then publish the flag
    asm volatile("s_waitcnt vmcnt(0)" ::: "memory");
    __builtin_amdgcn_sched_barrier(0);
    if (lane == 0) STORE_SC(fown_ptr, (u32)(t + 1));
  }
}

// ---------------- head: logits = h1_last @ w_lin^T + b_lin ----------------
__global__ __launch_bounds__(64) void logits_kernel(const u32* __restrict__ hpk,  // packed [64][1024]
                                                    const u16* __restrict__ wl,   // [1008][1024]
                                                    const float* __restrict__ blin,
                                                    float* __restrict__ lg) {     // [64][1008]
  const int wgn = blockIdx.x;  // 0..62
  const int lane = threadIdx.x;
  const int rl = lane & 15;
  const int q = lane >> 4;
  f32x4 acc[4] = {};
  const u16* brow = wl + (size_t)(wgn * 16 + rl) * 1024 + q * 8;
  for (int kt = 0; kt < 32; ++kt) {
    bf16x8 bfv = *(const bf16x8*)(brow + kt * 32);
#pragma unroll
    for (int mi = 0; mi < 4; ++mi) {
      const u32* hp = hpk + (mi * 16 + rl) * 1024 + kt * 32 + q * 8;
      u32x4 d0 = *(const u32x4*)hp;
      u32x4 d1 = *(const u32x4*)(hp + 4);
      acc[mi] = MFMA_BF16(hi_frag(d0, d1), bfv, acc[mi]);
      acc[mi] = MFMA_BF16(lo_frag(d0, d1), bfv, acc[mi]);
    }
  }
  int col = wgn * 16 + rl;
  float bb = (col < 1000) ? blin[col] : 0.f;
#pragma unroll
  for (int mi = 0; mi < 4; ++mi)
#pragma unroll
    for (int r = 0; r < 4; ++r) {
      int row = mi * 16 + q * 4 + r;
      lg[row * 1008 + col] = acc[mi][r] + bb;
    }
}

__global__ __launch_bounds__(64) void lsm_kernel(const float* __restrict__ lg,
                                                 float* __restrict__ outp) {
  const int b = blockIdx.x;
  const int lane = threadIdx.x;
  float x[16];
  float m = -1e30f;
#pragma unroll
  for (int i = 0; i < 16; ++i) {
    int o = lane + i * 64;
    x[i] = (o < 1000) ? lg[b * 1008 + o] : -1e30f;
    m = fmaxf(m, x[i]);
  }
  for (int s = 32; s > 0; s >>= 1) m = fmaxf(m, __shfl_xor(m, s, 64));
  float sum = 0.f;
#pragma unroll
  for (int i = 0; i < 16; ++i) sum += expf(x[i] - m);
  for (int s = 32; s > 0; s >>= 1) sum += __shfl_xor(sum, s, 64);
  float lse = m + logf(sum);
#pragma unroll
  for (int i = 0; i < 16; ++i) {
    int o = lane + i * 64;
    if (o < 1000) outp[b * 1000 + o] = x[i] - lse;
  }
}

// ---------------- launch ----------------
extern "C" void kernel_launch(void* const* d_in, const int* in_sizes, int n_in,
                              void* d_out, int out_size, void* d_ws, size_t ws_size,
                              hipStream_t stream) {
  (void)in_sizes; (void)n_in; (void)out_size;
  const int B = 64, T = 512, I = 256, H = 1024, O = 1000;

  const float* x = (const float*)d_in[0];
  const float* w_ih0 = (const float*)d_in[1];
  const float* w_hh0 = (const float*)d_in[2];
  const float* b_ih0 = (const float*)d_in[3];
  const float* b_hh0 = (const float*)d_in[4];
  const float* w_ih1 = (const float*)d_in[5];
  const float* w_hh1 = (const float*)d_in[6];
  const float* b_ih1 = (const float*)d_in[7];
  const float* b_hh1 = (const float*)d_in[8];
  const float* w_lin = (const float*)d_in[9];
  const float* b_lin = (const float*)d_in[10];

  size_t off = 0;
  char* ws = (char*)d_ws;
  auto take = [&](size_t bytes) -> void* {
    void* p = ws + off;
    off += (bytes + 255) & ~(size_t)255;
    return p;
  };
  u16* pre = (u16*)take((size_t)T * B * H * 2);   // 64MB
  u16* xbf = (u16*)take((size_t)B * T * I * 2);   // 16MB
  u16* wih0b = (u16*)take((size_t)H * I * 2);
  u16* whh0b = (u16*)take((size_t)H * H * 2);
  u16* wih1b = (u16*)take((size_t)H * H * 2);
  u16* whh1b = (u16*)take((size_t)H * H * 2);
  u16* wlinb = (u16*)take((size_t)1008 * H * 2);
  float* bv0 = (float*)take((size_t)H * 4);
  float* bv1 = (float*)take((size_t)H * 4);
  u32* h0buf = (u32*)take((size_t)4 * B * H * 4);  // packed hi|lo, 4-deep
  u32* h1buf = (u32*)take((size_t)4 * B * H * 4);
  u32* hlast = (u32*)take((size_t)B * H * 4);      // normal-path export of h1(T-1)
  u32* F0 = (u32*)take((size_t)4 * 32 * 4);
  u32* F1 = (u32*)take((size_t)4 * 32 * 4);
  float* lgt = (float*)take((size_t)B * 1008 * 4);
  if (off > ws_size) return;

  // casts
  cast_kernel<<<(B * T * I / 4) / 256, 256, 0, stream>>>(x, xbf, B * T * I / 4);
  cast_kernel<<<(H * I / 4) / 256, 256, 0, stream>>>(w_ih0, wih0b, H * I / 4);
  cast_kernel<<<(H * H / 4) / 256, 256, 0, stream>>>(w_hh0, whh0b, H * H / 4);
  cast_kernel<<<(H * H / 4) / 256, 256, 0, stream>>>(w_ih1, wih1b, H * H / 4);
  cast_kernel<<<(H * H / 4) / 256, 256, 0, stream>>>(w_hh1, whh1b, H * H / 4);
  cast_kernel<<<(O * H / 4) / 256, 256, 0, stream>>>(w_lin, wlinb, O * H / 4);
  bias_kernel<<<4, 256, 0, stream>>>(b_ih0, b_hh0, bv0, H);
  bias_kernel<<<4, 256, 0, stream>>>(b_ih1, b_hh1, bv1, H);

  // zero h-buffers + flags through the bypass path
  init_sync_kernel<<<1024, 256, 0, stream>>>(h0buf, h1buf, F0, F1);

  gemm_pre<<<dim3((B * T / 128) * (H / 128)), 256, 0, stream>>>(xbf, wih0b, pre, I);

  // persistent fused scan: 256 single-wave blocks, 128KB LDS each ->
  // 1 block/CU on 256 CUs; all blocks co-resident (normal launch).
  fused_scan<<<256, 64, 0, stream>>>(whh0b, whh1b, wih1b, pre, bv0, bv1,
                                     h0buf, h1buf, F0, F1, hlast);

  logits_kernel<<<63, 64, 0, stream>>>(hlast, wlinb, b_lin, lgt);
  lsm_kernel<<<64, 64, 0, stream>>>(lgt, (float*)d_out);
}